// Round 6
// baseline (344.605 us; speedup 1.0000x reference)
//
#include <hip/hip_runtime.h>
#include <hip/hip_bf16.h>

#define T_DIM 200
#define U_DIM 100
#define U1    101
#define H_DIM 320
#define K_INNER 512
#define V_DIM 1000
#define B_DIM 4
#define DP_PITCH 128
#define ND 300            // diagonals d = t+u in [0, 299]
#define ROWS 64           // 16 t x 4 u per block

typedef unsigned short ushort_t;
typedef unsigned int uint32;

typedef short bfrag8 __attribute__((ext_vector_type(8)));
typedef float ffrag4 __attribute__((ext_vector_type(4)));

#define LOG2E 1.4426950408889634f
#define LN2   0.6931471805599453f

__device__ __forceinline__ uint32 pk_bf16(float a, float b) {
  __hip_bfloat162 h = __float22bfloat162_rn(make_float2(a, b));
  return *(uint32*)&h;
}

__device__ __forceinline__ float tanh_fast(float x) {
  float e = __expf(2.0f * x);                 // inf-safe: e=inf -> 1, e=0 -> -1
  return 1.0f - __fdividef(2.0f, e + 1.0f);
}

// ---------------- fused prep:
//   blocks [0,100):   h_enc projection (8 rows each)
//   blocks [100,151): h_dec projection (8 rows each)
//   blocks [151,215): W2 transpose-pack -> W2f[kchunk 64][n 1024][8 shorts]
__global__ __launch_bounds__(512)
void prep_kernel(const float* __restrict__ enc, const float* __restrict__ dec,
                 const float* __restrict__ W1, const float* __restrict__ W2,
                 float* __restrict__ hEnc, float* __restrict__ hDec,
                 ushort_t* __restrict__ W2f)
{
  __shared__ union { float sIn[8][H_DIM]; float sW[8][1024]; } sh;
  const int tid = threadIdx.x;
  const int blk = blockIdx.x;

  if (blk < 151) {
    const float* inp; float* outp; int nRows, rowOff, b0;
    if (blk < 100) { inp = enc; outp = hEnc; nRows = B_DIM * T_DIM; rowOff = 0;     b0 = blk; }
    else           { inp = dec; outp = hDec; nRows = B_DIM * U1;    rowOff = H_DIM; b0 = blk - 100; }
    const int r0 = b0 * 8;
    for (int i = tid; i < 8 * H_DIM; i += 512) {
      int r = i / H_DIM, k = i - r * H_DIM;
      int rr = r0 + r;
      sh.sIn[r][k] = (rr < nRows) ? inp[(size_t)rr * H_DIM + k] : 0.0f;
    }
    __syncthreads();
    const int c = tid;  // 0..511
    float acc[8];
#pragma unroll
    for (int r = 0; r < 8; ++r) acc[r] = 0.0f;
    const float* Wp = W1 + (size_t)rowOff * K_INNER + c;
    for (int k = 0; k < H_DIM; k += 4) {
      float w0 = Wp[(size_t)(k + 0) * K_INNER];
      float w1 = Wp[(size_t)(k + 1) * K_INNER];
      float w2 = Wp[(size_t)(k + 2) * K_INNER];
      float w3 = Wp[(size_t)(k + 3) * K_INNER];
#pragma unroll
      for (int r = 0; r < 8; ++r) {
        float4 s = *(const float4*)&sh.sIn[r][k];
        acc[r] = fmaf(s.w, w3, fmaf(s.z, w2, fmaf(s.y, w1, fmaf(s.x, w0, acc[r]))));
      }
    }
#pragma unroll
    for (int r = 0; r < 8; ++r) {
      int rr = r0 + r;
      if (rr < nRows) outp[(size_t)rr * K_INNER + c] = acc[r];
    }
  } else {
    // W2 pack: kchunk kc covers k in [kc*8, kc*8+8); LDS transpose for coalesced R+W
    const int kc = blk - 151;
    for (int i = tid; i < 8 * 1024; i += 512) {
      int r = i >> 10, n = i & 1023;
      sh.sW[r][n] = (n < V_DIM) ? W2[(size_t)(kc * 8 + r) * V_DIM + n] : 0.0f;
    }
    __syncthreads();
#pragma unroll
    for (int h = 0; h < 2; ++h) {
      int n = tid + h * 512;
      uint4 pk;
      pk.x = pk_bf16(sh.sW[0][n], sh.sW[1][n]);
      pk.y = pk_bf16(sh.sW[2][n], sh.sW[3][n]);
      pk.z = pk_bf16(sh.sW[4][n], sh.sW[5][n]);
      pk.w = pk_bf16(sh.sW[6][n], sh.sW[7][n]);
      *(uint4*)&W2f[((size_t)kc * 1024 + n) * 8] = pk;
    }
  }
}

// ---------------- fused joint, 64-row tile (16t x 4u), 512 threads (8 waves),
// 64KB LDS -> 2 blocks/CU but 16 waves/CU (50% occupancy cap).
// Wave = (row-half rh, col-quarter cq): 32 rows x 256 cols per wave.
// The two row-halves stream the same B lines near-simultaneously -> L1 dedup,
// so per-block L2 B-traffic stays ~1MB; 1352 blocks -> 1.35GB (~39us floor).
// launch_bounds (512,4): VGPR cap 128, est ~100 used -> no spill (watch WRITE_SIZE).
__global__ __launch_bounds__(512, 4)
void joint_kernel(const float* __restrict__ hEnc, const float* __restrict__ hDec,
                  const float* __restrict__ b1, const ushort_t* __restrict__ W2f,
                  const float* __restrict__ b2, const int* __restrict__ tokens,
                  float* __restrict__ blankD, float* __restrict__ labelD)
{
  __shared__ union SU {
    ushort_t X[ROWS * K_INNER];   // 64 rows x 64 granules of 8 bf16, swizzled (64KB)
    float red[8][32][4];
  } sh;

  const int tid = threadIdx.x;
  const int b  = blockIdx.z;
  const int t0 = blockIdx.y * 16;   // 13 blocks cover 200 (writes guarded)
  const int u0 = blockIdx.x * 4;    // 26 blocks cover 104 >= 101

  // ---- X staging: 4096 granules, 8 per thread; per pass a wave owns one row
  // (row uniform per wave, G = lane -> conflict-free b128 writes)
#pragma unroll
  for (int j = 0; j < 8; ++j) {
    const int i = tid + j * 512;
    const int row = i >> 6;           // 0..63
    const int G = i & 63;
    const int tcl = min(t0 + (row >> 2), T_DIM - 1);
    const int ucl = min(u0 + (row & 3), U1 - 1);
    const float* er = hEnc + (size_t)(b * T_DIM + tcl) * K_INNER;
    const float* dr = hDec + (size_t)(b * U1 + ucl) * K_INNER;
    const int k = G << 3;
    float4 e0 = *(const float4*)(er + k);
    float4 e1 = *(const float4*)(er + k + 4);
    float4 d0 = *(const float4*)(dr + k);
    float4 d1 = *(const float4*)(dr + k + 4);
    float4 c0 = *(const float4*)(b1 + k);
    float4 c1 = *(const float4*)(b1 + k + 4);
    uint4 pk;
    pk.x = pk_bf16(tanh_fast(e0.x + d0.x + c0.x), tanh_fast(e0.y + d0.y + c0.y));
    pk.y = pk_bf16(tanh_fast(e0.z + d0.z + c0.z), tanh_fast(e0.w + d0.w + c0.w));
    pk.z = pk_bf16(tanh_fast(e1.x + d1.x + c1.x), tanh_fast(e1.y + d1.y + c1.y));
    pk.w = pk_bf16(tanh_fast(e1.z + d1.z + c1.z), tanh_fast(e1.w + d1.w + c1.w));
    const int slot = (G + row) & 63;
    *(uint4*)&sh.X[row * K_INNER + (slot << 3)] = pk;
  }
  __syncthreads();

  const int wave = tid >> 6;
  const int lane = tid & 63;
  const int l15 = lane & 15;
  const int quad = lane >> 4;
  const int rh = wave >> 2;         // row half: rows rh*32 .. rh*32+31
  const int cq = wave & 3;          // col quarter: cols cq*256 .. cq*256+255

  float sumexp[2][4], labelA[2][4], blankV[2][4];
#pragma unroll
  for (int i = 0; i < 2; ++i)
#pragma unroll
    for (int j = 0; j < 4; ++j) { sumexp[i][j] = 0.0f; labelA[i][j] = 0.0f; blankV[i][j] = 0.0f; }

  int tokv[4];
#pragma unroll
  for (int j = 0; j < 4; ++j)
    tokv[j] = (u0 + j < U_DIM) ? tokens[b * U_DIM + u0 + j] : -1;

#pragma unroll 1
  for (int ct = 0; ct < 4; ++ct) {
    const int nbase = cq * 256 + ct * 64;
    ffrag4 acc[2][4];
    ffrag4 zero4 = {0.0f, 0.0f, 0.0f, 0.0f};
#pragma unroll
    for (int rb = 0; rb < 2; ++rb)
#pragma unroll
      for (int cb = 0; cb < 4; ++cb) acc[rb][cb] = zero4;

#pragma unroll 4
    for (int ks = 0; ks < 16; ++ks) {
      const int kchunk = ks * 4 + quad;
      bfrag8 av[2];
#pragma unroll
      for (int rb = 0; rb < 2; ++rb) {
        const int m = rh * 32 + rb * 16 + l15;
        const int slot = (kchunk + m) & 63;
        av[rb] = *(const bfrag8*)&sh.X[m * K_INNER + (slot << 3)];
      }
      bfrag8 bv[4];
#pragma unroll
      for (int cb = 0; cb < 4; ++cb) {
        const int n = nbase + cb * 16 + l15;
        bv[cb] = *(const bfrag8*)(W2f + ((size_t)kchunk * 1024 + n) * 8);
      }
#pragma unroll
      for (int rb = 0; rb < 2; ++rb)
#pragma unroll
        for (int cb = 0; cb < 4; ++cb)
          acc[rb][cb] = __builtin_amdgcn_mfma_f32_16x16x32_bf16(av[rb], bv[cb], acc[rb][cb], 0, 0, 0);
    }

    // epilogue: online sum(exp) via exp2, raw label capture (b2 folded at the end)
#pragma unroll
    for (int cb = 0; cb < 4; ++cb) {
      const int v = nbase + cb * 16 + l15;
      const float b2v = (v < V_DIM) ? b2[v] : -1e30f;
      const float b2s = b2v * LOG2E;
#pragma unroll
      for (int rb = 0; rb < 2; ++rb)
#pragma unroll
        for (int reg = 0; reg < 4; ++reg) {
          float a = acc[rb][cb][reg];
          sumexp[rb][reg] += exp2f(fmaf(a, LOG2E, b2s));
          labelA[rb][reg] += (v == tokv[reg]) ? a : 0.0f;
        }
    }
    if (nbase == 0) {   // cq 0, ct 0: v==0 column lives on l15==0 lanes of cb 0
#pragma unroll
      for (int rb = 0; rb < 2; ++rb)
#pragma unroll
        for (int reg = 0; reg < 4; ++reg) blankV[rb][reg] = acc[rb][0][reg];
    }
  }

#pragma unroll
  for (int mask = 1; mask <= 8; mask <<= 1) {
#pragma unroll
    for (int rb = 0; rb < 2; ++rb)
#pragma unroll
      for (int reg = 0; reg < 4; ++reg) {
        sumexp[rb][reg] += __shfl_xor(sumexp[rb][reg], mask, 64);
        labelA[rb][reg] += __shfl_xor(labelA[rb][reg], mask, 64);
      }
  }

  __syncthreads();   // X reads done -> reuse union as red[]
  if (l15 == 0) {
#pragma unroll
    for (int rb = 0; rb < 2; ++rb)
#pragma unroll
      for (int reg = 0; reg < 4; ++reg) {
        int rg = rb * 16 + quad * 4 + reg;   // row within the 32-row group
        sh.red[wave][rg][0] = sumexp[rb][reg];
        sh.red[wave][rg][1] = blankV[rb][reg];
        sh.red[wave][rg][2] = labelA[rb][reg];
      }
  }
  __syncthreads();
  if (tid < ROWS) {
    const int rhh = tid >> 5;        // which row half
    const int rg = tid & 31;
    float S  = sh.red[rhh*4+0][rg][0] + sh.red[rhh*4+1][rg][0] + sh.red[rhh*4+2][rg][0] + sh.red[rhh*4+3][rg][0];
    float Bl = sh.red[rhh*4+0][rg][1] + sh.red[rhh*4+1][rg][1] + sh.red[rhh*4+2][rg][1] + sh.red[rhh*4+3][rg][1];
    float Lb = sh.red[rhh*4+0][rg][2] + sh.red[rhh*4+1][rg][2] + sh.red[rhh*4+2][rg][2] + sh.red[rhh*4+3][rg][2];
    int t = t0 + (tid >> 2);
    int u = u0 + (tid & 3);
    if (t < T_DIM && u < U1) {
      float lse2 = __log2f(S);                 // S = sum(exp(logit))
      int tok = (u < U_DIM) ? tokens[b * U_DIM + u] : 0;
      int d = t + u;
      size_t idx = ((size_t)b * ND + d) * DP_PITCH + u;
      // store log2-domain log-probs for the DP
      blankD[idx] = (Bl + b2[0])   * LOG2E - lse2;
      labelD[idx] = (Lb + b2[tok]) * LOG2E - lse2;
    }
  }
}

// ---------------- RNNT DP over diagonals, log2 domain, named-register pipeline
__global__ __launch_bounds__(256)
void dp_kernel(const float* __restrict__ blankD, const float* __restrict__ labelD,
               const int* __restrict__ outLen, const int* __restrict__ tokLen,
               float* __restrict__ outLoss)
{
  __shared__ float llsh[B_DIM];
  const int tid = threadIdx.x;
  const int wv = tid >> 6;
  const int lane = tid & 63;
  const float* bD = blankD + (size_t)wv * ND * DP_PITCH;
  const float* lD = labelD + (size_t)wv * ND * DP_PITCH;
  const int tIdx = outLen[wv] - 1;
  const int uIdx = tokLen[wv];
  const int dStar = tIdx + uIdx;
  const float NEG = -1e30f;

  float aE = (lane == 0) ? 0.0f : NEG;   // log2(1) = 0
  float aO = NEG;
  float ll2 = 0.0f;
  if (dStar == 0 && lane == 0) ll2 = bD[0];

  const int uE = 2 * lane, uO = uE + 1;

#define LDB(dg) (*(const float2*)&bD[(size_t)(dg) * DP_PITCH + uE])
#define LDL(dg) (*(const float2*)&lD[(size_t)(dg) * DP_PITCH + uE])

  float2 B0 = LDB(0), L0 = LDL(0);
  float2 B1 = LDB(1), L1 = LDL(1);
  float2 B2 = LDB(2), L2 = LDL(2);
  float2 B3 = LDB(3), L3 = LDL(3);

#define DPSTEP(d, Bv, Lv)                                                    \
  {                                                                          \
    float aO_up = __shfl_up(aO, 1, 64);                                      \
    if (lane == 0) aO_up = NEG;                                              \
    float labUp = __shfl_up(Lv.y, 1, 64);                                    \
    float bt0 = aE + Bv.x, lt0 = aO_up + labUp;                              \
    float mx0 = fmaxf(bt0, lt0), mn0 = fminf(bt0, lt0);                      \
    float r0 = mx0 + __log2f(1.0f + exp2f(mn0 - mx0));                       \
    int te = (d) - uE;                                                       \
    float nE = ((uE <= U_DIM) && (te >= 0) && (te < T_DIM)) ? r0 : NEG;      \
    float bt1 = aO + Bv.y, lt1 = aE + Lv.x;                                  \
    float mx1 = fmaxf(bt1, lt1), mn1 = fminf(bt1, lt1);                      \
    float r1 = mx1 + __log2f(1.0f + exp2f(mn1 - mx1));                       \
    int to = (d) - uO;                                                       \
    float nO = ((uO <= U_DIM) && (to >= 0) && (to < T_DIM)) ? r1 : NEG;      \
    aE = nE; aO = nO;                                                        \
    if ((d) == dStar) {                                                      \
      float blk = bD[(size_t)(d) * DP_PITCH + uIdx];                         \
      if (uIdx == uE)      ll2 = nE + blk;                                   \
      else if (uIdx == uO) ll2 = nO + blk;                                   \
    }                                                                        \
  }

  // groups of 4: base = 1,5,...,293 covers d = 1..296; tail d = 297..299
  for (int base = 1; base <= 293; base += 4) {
    DPSTEP(base + 0, B0, L0); B0 = LDB(base + 3); L0 = LDL(base + 3);
    DPSTEP(base + 1, B1, L1); B1 = LDB(base + 4); L1 = LDL(base + 4);
    DPSTEP(base + 2, B2, L2); B2 = LDB(base + 5); L2 = LDL(base + 5);
    DPSTEP(base + 3, B3, L3); B3 = LDB(base + 6); L3 = LDL(base + 6);
  }
  DPSTEP(297, B0, L0);
  DPSTEP(298, B1, L1);
  DPSTEP(299, B2, L2);

#undef DPSTEP
#undef LDB
#undef LDL

#pragma unroll
  for (int mask = 1; mask < 64; mask <<= 1) ll2 += __shfl_xor(ll2, mask, 64);
  if (lane == 0) llsh[wv] = ll2;
  __syncthreads();
  if (tid == 0)
    outLoss[0] = -(llsh[0] + llsh[1] + llsh[2] + llsh[3]) * 0.25f * LN2;
}

// ---------------- launch
extern "C" void kernel_launch(void* const* d_in, const int* in_sizes, int n_in,
                              void* d_out, int out_size, void* d_ws, size_t ws_size,
                              hipStream_t stream)
{
  const float* enc    = (const float*)d_in[0];
  const float* dec    = (const float*)d_in[1];
  const int*   tokens = (const int*)d_in[2];
  const int*   outLen = (const int*)d_in[3];
  const int*   tokLen = (const int*)d_in[4];
  const float* W1     = (const float*)d_in[5];
  const float* b1     = (const float*)d_in[6];
  const float* W2     = (const float*)d_in[7];
  const float* b2     = (const float*)d_in[8];
  float* out = (float*)d_out;

  char* ws = (char*)d_ws;
  float*    hEnc   = (float*)(ws + 0);           // 800*512*4   = 1,638,400
  float*    hDec   = (float*)(ws + 1638400);     // 404*512*4   =   827,392
  ushort_t* W2f    = (ushort_t*)(ws + 2465792);  // 64*1024*8*2 = 1,048,576
  float*    blankD = (float*)(ws + 3514368);     // 4*300*128*4 =   614,400
  float*    labelD = (float*)(ws + 4128768);     // 4*300*128*4 =   614,400  (end 4,743,168)

  prep_kernel<<<dim3(215), dim3(512), 0, stream>>>(enc, dec, W1, W2, hEnc, hDec, W2f);
  joint_kernel<<<dim3(26, 13, B_DIM), dim3(512), 0, stream>>>(hEnc, hDec, b1, W2f, b2, tokens, blankD, labelD);
  dp_kernel<<<dim3(1), dim3(256), 0, stream>>>(blankD, labelD, outLen, tokLen, out);
}

// Round 7
// 303.071 us; speedup vs baseline: 1.1370x; 1.1370x over previous
//
#include <hip/hip_runtime.h>
#include <hip/hip_bf16.h>

#define T_DIM 200
#define U_DIM 100
#define U1    101
#define H_DIM 320
#define K_INNER 512
#define V_DIM 1000
#define B_DIM 4
#define DP_PITCH 128
#define ND 300            // diagonals d = t+u in [0, 299]
#define ROWS 48           // 12 t x 4 u per block

typedef unsigned short ushort_t;
typedef unsigned char uchar_t;
typedef unsigned int uint32;
typedef long lfrag;       // 8 x fp8 = 2 VGPRs

typedef float ffrag4 __attribute__((ext_vector_type(4)));

#define LOG2E   1.4426950408889634f
#define LOG2E16 (1.4426950408889634f * 0.0625f)   // LOG2E/16 (W2 packed with x16 scale)
#define LN2     0.6931471805599453f

__device__ __forceinline__ uint32 pk_bf16(float a, float b) {
  __hip_bfloat162 h = __float22bfloat162_rn(make_float2(a, b));
  return *(uint32*)&h;
}

__device__ __forceinline__ float tanh_fast(float x) {
  float e = __expf(2.0f * x);                 // inf-safe: e=inf -> 1, e=0 -> -1
  return 1.0f - __fdividef(2.0f, e + 1.0f);
}

// pack 8 floats -> 8 fp8 e4m3 bytes (uint2) via hw cvt_pk
__device__ __forceinline__ uint2 pk_fp8x8(float t0, float t1, float t2, float t3,
                                          float t4, float t5, float t6, float t7) {
  uint2 r;
  r.x = (uint32)__builtin_amdgcn_cvt_pk_fp8_f32(t0, t1, 0, false);
  r.x = (uint32)__builtin_amdgcn_cvt_pk_fp8_f32(t2, t3, (int)r.x, true);
  r.y = (uint32)__builtin_amdgcn_cvt_pk_fp8_f32(t4, t5, 0, false);
  r.y = (uint32)__builtin_amdgcn_cvt_pk_fp8_f32(t6, t7, (int)r.y, true);
  return r;
}

// ---------------- fused prep:
//   blocks [0,100):   h_enc projection (8 rows each)
//   blocks [100,151): h_dec projection (8 rows each)
//   blocks [151,215): W2 transpose-pack (x16 scale) -> W2f8[kchunk 64][n 1024][8 fp8]
__global__ __launch_bounds__(512)
void prep_kernel(const float* __restrict__ enc, const float* __restrict__ dec,
                 const float* __restrict__ W1, const float* __restrict__ W2,
                 float* __restrict__ hEnc, float* __restrict__ hDec,
                 uchar_t* __restrict__ W2f8)
{
  __shared__ union { float sIn[8][H_DIM]; float sW[8][1024]; } sh;
  const int tid = threadIdx.x;
  const int blk = blockIdx.x;

  if (blk < 151) {
    const float* inp; float* outp; int nRows, rowOff, b0;
    if (blk < 100) { inp = enc; outp = hEnc; nRows = B_DIM * T_DIM; rowOff = 0;     b0 = blk; }
    else           { inp = dec; outp = hDec; nRows = B_DIM * U1;    rowOff = H_DIM; b0 = blk - 100; }
    const int r0 = b0 * 8;
    for (int i = tid; i < 8 * H_DIM; i += 512) {
      int r = i / H_DIM, k = i - r * H_DIM;
      int rr = r0 + r;
      sh.sIn[r][k] = (rr < nRows) ? inp[(size_t)rr * H_DIM + k] : 0.0f;
    }
    __syncthreads();
    const int c = tid;  // 0..511
    float acc[8];
#pragma unroll
    for (int r = 0; r < 8; ++r) acc[r] = 0.0f;
    const float* Wp = W1 + (size_t)rowOff * K_INNER + c;
    for (int k = 0; k < H_DIM; k += 4) {
      float w0 = Wp[(size_t)(k + 0) * K_INNER];
      float w1 = Wp[(size_t)(k + 1) * K_INNER];
      float w2 = Wp[(size_t)(k + 2) * K_INNER];
      float w3 = Wp[(size_t)(k + 3) * K_INNER];
#pragma unroll
      for (int r = 0; r < 8; ++r) {
        float4 s = *(const float4*)&sh.sIn[r][k];
        acc[r] = fmaf(s.w, w3, fmaf(s.z, w2, fmaf(s.y, w1, fmaf(s.x, w0, acc[r]))));
      }
    }
#pragma unroll
    for (int r = 0; r < 8; ++r) {
      int rr = r0 + r;
      if (rr < nRows) outp[(size_t)rr * K_INNER + c] = acc[r];
    }
  } else {
    // W2 pack: kchunk kc covers k in [kc*8, kc*8+8); LDS transpose; x16 scale
    // (raw |w| <= 0.045 sits in e4m3's denormal zone; x16 -> +-0.71, normal)
    const int kc = blk - 151;
    for (int i = tid; i < 8 * 1024; i += 512) {
      int r = i >> 10, n = i & 1023;
      sh.sW[r][n] = (n < V_DIM) ? W2[(size_t)(kc * 8 + r) * V_DIM + n] : 0.0f;
    }
    __syncthreads();
#pragma unroll
    for (int h = 0; h < 2; ++h) {
      int n = tid + h * 512;
      uint2 pk = pk_fp8x8(sh.sW[0][n] * 16.f, sh.sW[1][n] * 16.f,
                          sh.sW[2][n] * 16.f, sh.sW[3][n] * 16.f,
                          sh.sW[4][n] * 16.f, sh.sW[5][n] * 16.f,
                          sh.sW[6][n] * 16.f, sh.sW[7][n] * 16.f);
      *(uint2*)&W2f8[((size_t)kc * 1024 + n) * 8] = pk;
    }
  }
}

// ---------------- fused joint, fp8 operands, 48-row tile (12t x 4u), 24KB LDS.
// X and W2 in fp8 e4m3 (OCP): halves LDS (48->24KB), W2 L2-stream (1->0.5MB/blk)
// and fragment registers vs bf16. Same 16x16x32 shape (fp8 = bf16 MFMA rate).
// launch_bounds (256,4): 128-reg cap; fp8 frag savings should fit (~114 est).
// Tripwire: if WRITE_SIZE balloons (scratch spill, cf. r4/r6), revert to (256,3).
__global__ __launch_bounds__(256, 4)
void joint_kernel(const float* __restrict__ hEnc, const float* __restrict__ hDec,
                  const float* __restrict__ b1, const uchar_t* __restrict__ W2f8,
                  const float* __restrict__ b2, const int* __restrict__ tokens,
                  float* __restrict__ blankD, float* __restrict__ labelD)
{
  __shared__ union SU {
    uchar_t X[ROWS * K_INNER];    // 48 rows x 64 granules of 8 fp8, swizzled (24KB)
    float red[4][ROWS][4];        // 3KB, reused after MFMA phase
  } sh;

  const int tid = threadIdx.x;
  const int b  = blockIdx.z;
  const int t0 = blockIdx.y * 12;   // 17 blocks cover 200 (writes guarded)
  const int u0 = blockIdx.x * 4;    // 26 blocks cover 104 >= 101

  // ---- X staging: 3072 granules of 8 fp8; per pass a wave owns one row
  // (row uniform per wave, G = lane -> conflict-free b64 writes)
  for (int i = tid; i < ROWS * 64; i += 256) {
    const int row = i >> 6;           // 0..47
    const int G = i & 63;
    const int tcl = min(t0 + (row >> 2), T_DIM - 1);
    const int ucl = min(u0 + (row & 3), U1 - 1);
    const float* er = hEnc + (size_t)(b * T_DIM + tcl) * K_INNER;
    const float* dr = hDec + (size_t)(b * U1 + ucl) * K_INNER;
    const int k = G << 3;
    float4 e0 = *(const float4*)(er + k);
    float4 e1 = *(const float4*)(er + k + 4);
    float4 d0 = *(const float4*)(dr + k);
    float4 d1 = *(const float4*)(dr + k + 4);
    float4 c0 = *(const float4*)(b1 + k);
    float4 c1 = *(const float4*)(b1 + k + 4);
    uint2 pk = pk_fp8x8(tanh_fast(e0.x + d0.x + c0.x), tanh_fast(e0.y + d0.y + c0.y),
                        tanh_fast(e0.z + d0.z + c0.z), tanh_fast(e0.w + d0.w + c0.w),
                        tanh_fast(e1.x + d1.x + c1.x), tanh_fast(e1.y + d1.y + c1.y),
                        tanh_fast(e1.z + d1.z + c1.z), tanh_fast(e1.w + d1.w + c1.w));
    const int slot = (G + row) & 63;
    *(uint2*)&sh.X[row * K_INNER + (slot << 3)] = pk;
  }
  __syncthreads();

  const int wave = tid >> 6;
  const int lane = tid & 63;
  const int l15 = lane & 15;
  const int quad = lane >> 4;

  float sumexp[3][4], labelA[3][4], blankV[3][4];
#pragma unroll
  for (int i = 0; i < 3; ++i)
#pragma unroll
    for (int j = 0; j < 4; ++j) { sumexp[i][j] = 0.0f; labelA[i][j] = 0.0f; blankV[i][j] = 0.0f; }

  int tokv[4];
#pragma unroll
  for (int j = 0; j < 4; ++j)
    tokv[j] = (u0 + j < U_DIM) ? tokens[b * U_DIM + u0 + j] : -1;

#pragma unroll 1
  for (int ct = 0; ct < 4; ++ct) {
    const int nbase = ct * 256 + wave * 64;
    ffrag4 acc[3][4];
    ffrag4 zero4 = {0.0f, 0.0f, 0.0f, 0.0f};
#pragma unroll
    for (int rb = 0; rb < 3; ++rb)
#pragma unroll
      for (int cb = 0; cb < 4; ++cb) acc[rb][cb] = zero4;

#pragma unroll 4
    for (int ks = 0; ks < 16; ++ks) {
      const int kchunk = ks * 4 + quad;
      lfrag av[3];
#pragma unroll
      for (int rb = 0; rb < 3; ++rb) {
        const int m = rb * 16 + l15;
        const int slot = (kchunk + m) & 63;
        av[rb] = *(const lfrag*)&sh.X[m * K_INNER + (slot << 3)];
      }
      lfrag bv[4];
#pragma unroll
      for (int cb = 0; cb < 4; ++cb) {
        const int n = nbase + cb * 16 + l15;
        bv[cb] = *(const lfrag*)(W2f8 + ((size_t)kchunk * 1024 + n) * 8);
      }
#pragma unroll
      for (int rb = 0; rb < 3; ++rb)
#pragma unroll
        for (int cb = 0; cb < 4; ++cb)
          acc[rb][cb] = __builtin_amdgcn_mfma_f32_16x16x32_fp8_fp8(av[rb], bv[cb], acc[rb][cb], 0, 0, 0);
    }

    // epilogue: acc = 16 x true logit (W2 scale); online sum(exp) via exp2
#pragma unroll
    for (int cb = 0; cb < 4; ++cb) {
      const int v = nbase + cb * 16 + l15;
      const float b2v = (v < V_DIM) ? b2[v] : -1e30f;
      const float b2s = b2v * LOG2E;
#pragma unroll
      for (int rb = 0; rb < 3; ++rb)
#pragma unroll
        for (int reg = 0; reg < 4; ++reg) {
          float a = acc[rb][cb][reg];
          sumexp[rb][reg] += exp2f(fmaf(a, LOG2E16, b2s));
          labelA[rb][reg] += (v == tokv[reg]) ? a : 0.0f;
        }
    }
    if (nbase == 0) {   // wave 0, ct 0: v==0 column lives on l15==0 lanes of cb 0
#pragma unroll
      for (int rb = 0; rb < 3; ++rb)
#pragma unroll
        for (int reg = 0; reg < 4; ++reg) blankV[rb][reg] = acc[rb][0][reg];
    }
  }

#pragma unroll
  for (int mask = 1; mask <= 8; mask <<= 1) {
#pragma unroll
    for (int rb = 0; rb < 3; ++rb)
#pragma unroll
      for (int reg = 0; reg < 4; ++reg) {
        sumexp[rb][reg] += __shfl_xor(sumexp[rb][reg], mask, 64);
        labelA[rb][reg] += __shfl_xor(labelA[rb][reg], mask, 64);
      }
  }

  __syncthreads();   // X reads done -> reuse union as red[]
  if (l15 == 0) {
#pragma unroll
    for (int rb = 0; rb < 3; ++rb)
#pragma unroll
      for (int reg = 0; reg < 4; ++reg) {
        int row = rb * 16 + quad * 4 + reg;
        sh.red[wave][row][0] = sumexp[rb][reg];
        sh.red[wave][row][1] = blankV[rb][reg];
        sh.red[wave][row][2] = labelA[rb][reg];
      }
  }
  __syncthreads();
  if (tid < ROWS) {
    float S  = sh.red[0][tid][0] + sh.red[1][tid][0] + sh.red[2][tid][0] + sh.red[3][tid][0];
    float Bl = sh.red[0][tid][1] + sh.red[1][tid][1] + sh.red[2][tid][1] + sh.red[3][tid][1];
    float Lb = sh.red[0][tid][2] + sh.red[1][tid][2] + sh.red[2][tid][2] + sh.red[3][tid][2];
    int t = t0 + (tid >> 2);
    int u = u0 + (tid & 3);
    if (t < T_DIM && u < U1) {
      float lse2 = __log2f(S);                 // S = sum(exp(true logit))
      int tok = (u < U_DIM) ? tokens[b * U_DIM + u] : 0;
      int d = t + u;
      size_t idx = ((size_t)b * ND + d) * DP_PITCH + u;
      // log2-domain log-probs for the DP; Bl/Lb carry the x16 scale
      blankD[idx] = fmaf(Bl, LOG2E16, b2[0]   * LOG2E) - lse2;
      labelD[idx] = fmaf(Lb, LOG2E16, b2[tok] * LOG2E) - lse2;
    }
  }
}

// ---------------- RNNT DP over diagonals, log2 domain, named-register pipeline.
// 8-deep prefetch: dp reads are cross-XCD (L3/HBM ~600-900cyc); 4-deep (~400cyc)
// was marginal.
__global__ __launch_bounds__(256)
void dp_kernel(const float* __restrict__ blankD, const float* __restrict__ labelD,
               const int* __restrict__ outLen, const int* __restrict__ tokLen,
               float* __restrict__ outLoss)
{
  __shared__ float llsh[B_DIM];
  const int tid = threadIdx.x;
  const int wv = tid >> 6;
  const int lane = tid & 63;
  const float* bD = blankD + (size_t)wv * ND * DP_PITCH;
  const float* lD = labelD + (size_t)wv * ND * DP_PITCH;
  const int tIdx = outLen[wv] - 1;
  const int uIdx = tokLen[wv];
  const int dStar = tIdx + uIdx;
  const float NEG = -1e30f;

  float aE = (lane == 0) ? 0.0f : NEG;   // log2(1) = 0
  float aO = NEG;
  float ll2 = 0.0f;
  if (dStar == 0 && lane == 0) ll2 = bD[0];

  const int uE = 2 * lane, uO = uE + 1;

#define LDB(dg) (*(const float2*)&bD[(size_t)(dg) * DP_PITCH + uE])
#define LDL(dg) (*(const float2*)&lD[(size_t)(dg) * DP_PITCH + uE])

  float2 B0 = LDB(0), L0 = LDL(0);
  float2 B1 = LDB(1), L1 = LDL(1);
  float2 B2 = LDB(2), L2 = LDL(2);
  float2 B3 = LDB(3), L3 = LDL(3);
  float2 B4 = LDB(4), L4 = LDL(4);
  float2 B5 = LDB(5), L5 = LDL(5);
  float2 B6 = LDB(6), L6 = LDL(6);
  float2 B7 = LDB(7), L7 = LDL(7);

#define DPSTEP(d, Bv, Lv)                                                    \
  {                                                                          \
    float aO_up = __shfl_up(aO, 1, 64);                                      \
    if (lane == 0) aO_up = NEG;                                              \
    float labUp = __shfl_up(Lv.y, 1, 64);                                    \
    float bt0 = aE + Bv.x, lt0 = aO_up + labUp;                              \
    float mx0 = fmaxf(bt0, lt0), mn0 = fminf(bt0, lt0);                      \
    float r0 = mx0 + __log2f(1.0f + exp2f(mn0 - mx0));                       \
    int te = (d) - uE;                                                       \
    float nE = ((uE <= U_DIM) && (te >= 0) && (te < T_DIM)) ? r0 : NEG;      \
    float bt1 = aO + Bv.y, lt1 = aE + Lv.x;                                  \
    float mx1 = fmaxf(bt1, lt1), mn1 = fminf(bt1, lt1);                      \
    float r1 = mx1 + __log2f(1.0f + exp2f(mn1 - mx1));                       \
    int to = (d) - uO;                                                       \
    float nO = ((uO <= U_DIM) && (to >= 0) && (to < T_DIM)) ? r1 : NEG;      \
    aE = nE; aO = nO;                                                        \
    if ((d) == dStar) {                                                      \
      float blk = bD[(size_t)(d) * DP_PITCH + uIdx];                         \
      if (uIdx == uE)      ll2 = nE + blk;                                   \
      else if (uIdx == uO) ll2 = nO + blk;                                   \
    }                                                                        \
  }

  // groups of 8: base = 1,9,...,289 covers d = 1..296; tail d = 297..299
  for (int base = 1; base <= 289; base += 8) {
    DPSTEP(base + 0, B0, L0); { int dg = min(base + 7,  299); B0 = LDB(dg); L0 = LDL(dg); }
    DPSTEP(base + 1, B1, L1); { int dg = min(base + 8,  299); B1 = LDB(dg); L1 = LDL(dg); }
    DPSTEP(base + 2, B2, L2); { int dg = min(base + 9,  299); B2 = LDB(dg); L2 = LDL(dg); }
    DPSTEP(base + 3, B3, L3); { int dg = min(base + 10, 299); B3 = LDB(dg); L3 = LDL(dg); }
    DPSTEP(base + 4, B4, L4); { int dg = min(base + 11, 299); B4 = LDB(dg); L4 = LDL(dg); }
    DPSTEP(base + 5, B5, L5); { int dg = min(base + 12, 299); B5 = LDB(dg); L5 = LDL(dg); }
    DPSTEP(base + 6, B6, L6); { int dg = min(base + 13, 299); B6 = LDB(dg); L6 = LDL(dg); }
    DPSTEP(base + 7, B7, L7); { int dg = min(base + 14, 299); B7 = LDB(dg); L7 = LDL(dg); }
  }
  DPSTEP(297, B0, L0);
  DPSTEP(298, B1, L1);
  DPSTEP(299, B2, L2);

#undef DPSTEP
#undef LDB
#undef LDL

#pragma unroll
  for (int mask = 1; mask < 64; mask <<= 1) ll2 += __shfl_xor(ll2, mask, 64);
  if (lane == 0) llsh[wv] = ll2;
  __syncthreads();
  if (tid == 0)
    outLoss[0] = -(llsh[0] + llsh[1] + llsh[2] + llsh[3]) * 0.25f * LN2;
}

// ---------------- launch
extern "C" void kernel_launch(void* const* d_in, const int* in_sizes, int n_in,
                              void* d_out, int out_size, void* d_ws, size_t ws_size,
                              hipStream_t stream)
{
  const float* enc    = (const float*)d_in[0];
  const float* dec    = (const float*)d_in[1];
  const int*   tokens = (const int*)d_in[2];
  const int*   outLen = (const int*)d_in[3];
  const int*   tokLen = (const int*)d_in[4];
  const float* W1     = (const float*)d_in[5];
  const float* b1     = (const float*)d_in[6];
  const float* W2     = (const float*)d_in[7];
  const float* b2     = (const float*)d_in[8];
  float* out = (float*)d_out;

  char* ws = (char*)d_ws;
  float*   hEnc   = (float*)(ws + 0);           // 800*512*4   = 1,638,400
  float*   hDec   = (float*)(ws + 1638400);     // 404*512*4   =   827,392
  uchar_t* W2f8   = (uchar_t*)(ws + 2465792);   // 64*1024*8   =   524,288
  float*   blankD = (float*)(ws + 2990080);     // 4*300*128*4 =   614,400
  float*   labelD = (float*)(ws + 3604480);     // 4*300*128*4 =   614,400  (end 4,218,880)

  prep_kernel<<<dim3(215), dim3(512), 0, stream>>>(enc, dec, W1, W2, hEnc, hDec, W2f8);
  joint_kernel<<<dim3(26, 17, B_DIM), dim3(256), 0, stream>>>(hEnc, hDec, b1, W2f8, b2, tokens, blankD, labelD);
  dp_kernel<<<dim3(1), dim3(256), 0, stream>>>(blankD, labelD, outLen, tokLen, out);
}

// Round 8
// 276.590 us; speedup vs baseline: 1.2459x; 1.0957x over previous
//
#include <hip/hip_runtime.h>
#include <hip/hip_bf16.h>

#define T_DIM 200
#define U_DIM 100
#define U1    101
#define H_DIM 320
#define K_INNER 512
#define V_DIM 1000
#define B_DIM 4
#define ND 300            // diagonals d = t+u in [0, 299]
#define ROWS 48           // 12 t x 4 u per block
#define CHUNK 8           // dp: diagonals per LDS chunk

typedef unsigned short ushort_t;
typedef unsigned char uchar_t;
typedef unsigned int uint32;
typedef long lfrag;       // 8 x fp8 = 2 VGPRs

typedef float ffrag4 __attribute__((ext_vector_type(4)));

#define LOG2E   1.4426950408889634f
#define LOG2E16 (1.4426950408889634f * 0.0625f)   // LOG2E/16 (W2 packed with x16 scale)
#define LN2     0.6931471805599453f

__device__ __forceinline__ float tanh_fast(float x) {
  float e = __expf(2.0f * x);                 // inf-safe: e=inf -> 1, e=0 -> -1
  return 1.0f - __fdividef(2.0f, e + 1.0f);
}

__device__ __forceinline__ uint2 pk_fp8x8(float t0, float t1, float t2, float t3,
                                          float t4, float t5, float t6, float t7) {
  uint2 r;
  r.x = (uint32)__builtin_amdgcn_cvt_pk_fp8_f32(t0, t1, 0, false);
  r.x = (uint32)__builtin_amdgcn_cvt_pk_fp8_f32(t2, t3, (int)r.x, true);
  r.y = (uint32)__builtin_amdgcn_cvt_pk_fp8_f32(t4, t5, 0, false);
  r.y = (uint32)__builtin_amdgcn_cvt_pk_fp8_f32(t6, t7, (int)r.y, true);
  return r;
}

// ---------------- fused prep:
//   blocks [0,100):   h_enc projection (8 rows each)
//   blocks [100,151): h_dec projection (8 rows each)
//   blocks [151,215): W2 transpose-pack (x16 scale) -> W2f8[kchunk 64][n 1024][8 fp8]
__global__ __launch_bounds__(512)
void prep_kernel(const float* __restrict__ enc, const float* __restrict__ dec,
                 const float* __restrict__ W1, const float* __restrict__ W2,
                 float* __restrict__ hEnc, float* __restrict__ hDec,
                 uchar_t* __restrict__ W2f8)
{
  __shared__ union { float sIn[8][H_DIM]; float sW[8][1024]; } sh;
  const int tid = threadIdx.x;
  const int blk = blockIdx.x;

  if (blk < 151) {
    const float* inp; float* outp; int nRows, rowOff, b0;
    if (blk < 100) { inp = enc; outp = hEnc; nRows = B_DIM * T_DIM; rowOff = 0;     b0 = blk; }
    else           { inp = dec; outp = hDec; nRows = B_DIM * U1;    rowOff = H_DIM; b0 = blk - 100; }
    const int r0 = b0 * 8;
    for (int i = tid; i < 8 * H_DIM; i += 512) {
      int r = i / H_DIM, k = i - r * H_DIM;
      int rr = r0 + r;
      sh.sIn[r][k] = (rr < nRows) ? inp[(size_t)rr * H_DIM + k] : 0.0f;
    }
    __syncthreads();
    const int c = tid;  // 0..511
    float acc[8];
#pragma unroll
    for (int r = 0; r < 8; ++r) acc[r] = 0.0f;
    const float* Wp = W1 + (size_t)rowOff * K_INNER + c;
    for (int k = 0; k < H_DIM; k += 4) {
      float w0 = Wp[(size_t)(k + 0) * K_INNER];
      float w1 = Wp[(size_t)(k + 1) * K_INNER];
      float w2 = Wp[(size_t)(k + 2) * K_INNER];
      float w3 = Wp[(size_t)(k + 3) * K_INNER];
#pragma unroll
      for (int r = 0; r < 8; ++r) {
        float4 s = *(const float4*)&sh.sIn[r][k];
        acc[r] = fmaf(s.w, w3, fmaf(s.z, w2, fmaf(s.y, w1, fmaf(s.x, w0, acc[r]))));
      }
    }
#pragma unroll
    for (int r = 0; r < 8; ++r) {
      int rr = r0 + r;
      if (rr < nRows) outp[(size_t)rr * K_INNER + c] = acc[r];
    }
  } else {
    // W2 pack: kchunk kc covers k in [kc*8, kc*8+8); LDS transpose; x16 scale
    // (raw |w| <= 0.045 sits in e4m3's denormal zone; x16 -> +-0.71, normal)
    const int kc = blk - 151;
    for (int i = tid; i < 8 * 1024; i += 512) {
      int r = i >> 10, n = i & 1023;
      sh.sW[r][n] = (n < V_DIM) ? W2[(size_t)(kc * 8 + r) * V_DIM + n] : 0.0f;
    }
    __syncthreads();
#pragma unroll
    for (int h = 0; h < 2; ++h) {
      int n = tid + h * 512;
      uint2 pk = pk_fp8x8(sh.sW[0][n] * 16.f, sh.sW[1][n] * 16.f,
                          sh.sW[2][n] * 16.f, sh.sW[3][n] * 16.f,
                          sh.sW[4][n] * 16.f, sh.sW[5][n] * 16.f,
                          sh.sW[6][n] * 16.f, sh.sW[7][n] * 16.f);
      *(uint2*)&W2f8[((size_t)kc * 1024 + n) * 8] = pk;
    }
  }
}

// ---------------- fused joint, fp8 operands, 48-row tile, 24KB LDS, (256,3).
// (256,4) spilled 14MB to scratch (r7); (256,3) fits cleanly (r5 evidence).
// Writes interleaved pD[b][d][u][{blank,label}] (log2 domain) for the DP.
__global__ __launch_bounds__(256, 3)
void joint_kernel(const float* __restrict__ hEnc, const float* __restrict__ hDec,
                  const float* __restrict__ b1, const uchar_t* __restrict__ W2f8,
                  const float* __restrict__ b2, const int* __restrict__ tokens,
                  float* __restrict__ pD)
{
  __shared__ union SU {
    uchar_t X[ROWS * K_INNER];    // 48 rows x 64 granules of 8 fp8, swizzled (24KB)
    float red[4][ROWS][4];
  } sh;

  const int tid = threadIdx.x;
  const int b  = blockIdx.z;
  const int t0 = blockIdx.y * 12;   // 17 blocks cover 200 (writes guarded)
  const int u0 = blockIdx.x * 4;    // 26 blocks cover 104 >= 101

  // ---- X staging: 3072 granules of 8 fp8; per pass a wave owns one row
  for (int i = tid; i < ROWS * 64; i += 256) {
    const int row = i >> 6;           // 0..47
    const int G = i & 63;
    const int tcl = min(t0 + (row >> 2), T_DIM - 1);
    const int ucl = min(u0 + (row & 3), U1 - 1);
    const float* er = hEnc + (size_t)(b * T_DIM + tcl) * K_INNER;
    const float* dr = hDec + (size_t)(b * U1 + ucl) * K_INNER;
    const int k = G << 3;
    float4 e0 = *(const float4*)(er + k);
    float4 e1 = *(const float4*)(er + k + 4);
    float4 d0 = *(const float4*)(dr + k);
    float4 d1 = *(const float4*)(dr + k + 4);
    float4 c0 = *(const float4*)(b1 + k);
    float4 c1 = *(const float4*)(b1 + k + 4);
    uint2 pk = pk_fp8x8(tanh_fast(e0.x + d0.x + c0.x), tanh_fast(e0.y + d0.y + c0.y),
                        tanh_fast(e0.z + d0.z + c0.z), tanh_fast(e0.w + d0.w + c0.w),
                        tanh_fast(e1.x + d1.x + c1.x), tanh_fast(e1.y + d1.y + c1.y),
                        tanh_fast(e1.z + d1.z + c1.z), tanh_fast(e1.w + d1.w + c1.w));
    const int slot = (G + row) & 63;
    *(uint2*)&sh.X[row * K_INNER + (slot << 3)] = pk;
  }
  __syncthreads();

  const int wave = tid >> 6;
  const int lane = tid & 63;
  const int l15 = lane & 15;
  const int quad = lane >> 4;

  float sumexp[3][4], labelA[3][4], blankV[3][4];
#pragma unroll
  for (int i = 0; i < 3; ++i)
#pragma unroll
    for (int j = 0; j < 4; ++j) { sumexp[i][j] = 0.0f; labelA[i][j] = 0.0f; blankV[i][j] = 0.0f; }

  int tokv[4];
#pragma unroll
  for (int j = 0; j < 4; ++j)
    tokv[j] = (u0 + j < U_DIM) ? tokens[b * U_DIM + u0 + j] : -1;

#pragma unroll 1
  for (int ct = 0; ct < 4; ++ct) {
    const int nbase = ct * 256 + wave * 64;
    ffrag4 acc[3][4];
    ffrag4 zero4 = {0.0f, 0.0f, 0.0f, 0.0f};
#pragma unroll
    for (int rb = 0; rb < 3; ++rb)
#pragma unroll
      for (int cb = 0; cb < 4; ++cb) acc[rb][cb] = zero4;

#pragma unroll 4
    for (int ks = 0; ks < 16; ++ks) {
      const int kchunk = ks * 4 + quad;
      lfrag av[3];
#pragma unroll
      for (int rb = 0; rb < 3; ++rb) {
        const int m = rb * 16 + l15;
        const int slot = (kchunk + m) & 63;
        av[rb] = *(const lfrag*)&sh.X[m * K_INNER + (slot << 3)];
      }
      lfrag bv[4];
#pragma unroll
      for (int cb = 0; cb < 4; ++cb) {
        const int n = nbase + cb * 16 + l15;
        bv[cb] = *(const lfrag*)(W2f8 + ((size_t)kchunk * 1024 + n) * 8);
      }
#pragma unroll
      for (int rb = 0; rb < 3; ++rb)
#pragma unroll
        for (int cb = 0; cb < 4; ++cb)
          acc[rb][cb] = __builtin_amdgcn_mfma_f32_16x16x32_fp8_fp8(av[rb], bv[cb], acc[rb][cb], 0, 0, 0);
    }

    // epilogue: acc = 16 x true logit (W2 scale); online sum(exp) via exp2
#pragma unroll
    for (int cb = 0; cb < 4; ++cb) {
      const int v = nbase + cb * 16 + l15;
      const float b2v = (v < V_DIM) ? b2[v] : -1e30f;
      const float b2s = b2v * LOG2E;
#pragma unroll
      for (int rb = 0; rb < 3; ++rb)
#pragma unroll
        for (int reg = 0; reg < 4; ++reg) {
          float a = acc[rb][cb][reg];
          sumexp[rb][reg] += exp2f(fmaf(a, LOG2E16, b2s));
          labelA[rb][reg] += (v == tokv[reg]) ? a : 0.0f;
        }
    }
    if (nbase == 0) {   // wave 0, ct 0: v==0 column lives on l15==0 lanes of cb 0
#pragma unroll
      for (int rb = 0; rb < 3; ++rb)
#pragma unroll
        for (int reg = 0; reg < 4; ++reg) blankV[rb][reg] = acc[rb][0][reg];
    }
  }

#pragma unroll
  for (int mask = 1; mask <= 8; mask <<= 1) {
#pragma unroll
    for (int rb = 0; rb < 3; ++rb)
#pragma unroll
      for (int reg = 0; reg < 4; ++reg) {
        sumexp[rb][reg] += __shfl_xor(sumexp[rb][reg], mask, 64);
        labelA[rb][reg] += __shfl_xor(labelA[rb][reg], mask, 64);
      }
  }

  __syncthreads();   // X reads done -> reuse union as red[]
  if (l15 == 0) {
#pragma unroll
    for (int rb = 0; rb < 3; ++rb)
#pragma unroll
      for (int reg = 0; reg < 4; ++reg) {
        int row = rb * 16 + quad * 4 + reg;
        sh.red[wave][row][0] = sumexp[rb][reg];
        sh.red[wave][row][1] = blankV[rb][reg];
        sh.red[wave][row][2] = labelA[rb][reg];
      }
  }
  __syncthreads();
  if (tid < ROWS) {
    float S  = sh.red[0][tid][0] + sh.red[1][tid][0] + sh.red[2][tid][0] + sh.red[3][tid][0];
    float Bl = sh.red[0][tid][1] + sh.red[1][tid][1] + sh.red[2][tid][1] + sh.red[3][tid][1];
    float Lb = sh.red[0][tid][2] + sh.red[1][tid][2] + sh.red[2][tid][2] + sh.red[3][tid][2];
    int t = t0 + (tid >> 2);
    int u = u0 + (tid & 3);
    if (t < T_DIM && u < U1) {
      float lse2 = __log2f(S);                 // S = sum(exp(true logit))
      int tok = (u < U_DIM) ? tokens[b * U_DIM + u] : 0;
      int d = t + u;
      size_t idx = (((size_t)b * ND + d) * 128 + u) * 2;
      pD[idx]     = fmaf(Bl, LOG2E16, b2[0]   * LOG2E) - lse2;   // blank
      pD[idx + 1] = fmaf(Lb, LOG2E16, b2[tok] * LOG2E) - lse2;   // label
    }
  }
}

// ---------------- RNNT DP, log2 domain, LDS-staged double-buffered chunks.
// r7 evidence: source-level register prefetch gets sunk by the allocator
// (VGPR_Count 36, ~1037 cyc/step = raw memory latency on the serial chain).
// Fix: DMA 8-diagonal chunks (8KB) to LDS via global_load_lds; explicit
// s_waitcnt vmcnt(8) (asm, memory clobber) keeps exactly one chunk in flight.
// Compute reads LDS (prefetchable via lgkmcnt) + one shfl per step.
// Steps run to 304: d>299 is inert (bounds masks give NEG; dStar<=299).
__global__ __launch_bounds__(256)
void dp_kernel(const float* __restrict__ pD,
               const int* __restrict__ outLen, const int* __restrict__ tokLen,
               float* __restrict__ outLoss)
{
  __shared__ float sD[4][2][CHUNK * 256];   // 64 KB: per-wave double buffer
  __shared__ float llsh[B_DIM];
  const int tid = threadIdx.x;
  const int wv = tid >> 6;                  // wave = batch
  const int lane = tid & 63;
  const float* src = pD + (size_t)wv * ND * 256;
  const int tIdx = outLen[wv] - 1;
  const int uIdx = tokLen[wv];
  const int dStar = tIdx + uIdx;
  const float NEG = -1e30f;
  const float blkStar = src[((size_t)dStar * 128 + uIdx) * 2];

  float aE = (lane == 0) ? 0.0f : NEG;      // log2 domain
  float aO = NEG;
  float ll2 = 0.0f;
  if (dStar == 0 && lane == 0) ll2 = blkStar;

  const int uE = 2 * lane;

#define ISSUE(c, buf)                                                         \
  {                                                                           \
    const float* g_ = src + (size_t)(c) * (CHUNK * 256);                      \
    float* l_ = &sD[wv][(buf)][0];                                            \
    _Pragma("unroll")                                                         \
    for (int j_ = 0; j_ < CHUNK; ++j_)                                        \
      __builtin_amdgcn_global_load_lds(                                       \
        (const __attribute__((address_space(1))) void*)(g_ + j_ * 256 + lane * 4), \
        (__attribute__((address_space(3))) void*)(l_ + j_ * 256), 16, 0, 0);  \
  }

  ISSUE(0, 0)
#pragma unroll 1
  for (int c = 0; c < 38; ++c) {
    if (c < 37) {
      ISSUE(c + 1, (c + 1) & 1)
      asm volatile("s_waitcnt vmcnt(8)" ::: "memory");   // chunk c resident
    } else {
      asm volatile("s_waitcnt vmcnt(0)" ::: "memory");
    }
    const float* buf = &sD[wv][c & 1][0];
#pragma unroll
    for (int j = 0; j < CHUNK; ++j) {
      const int d = c * CHUNK + 1 + j;
      float4 q = *(const float4*)&buf[j * 256 + uE * 2];
      // q = (B[uE], L[uE], B[uE+1], L[uE+1]) at source diag d-1
      float aO_up = __shfl_up(aO, 1, 64);
      if (lane == 0) aO_up = NEG;
      float labUp = __shfl_up(q.w, 1, 64);            // L[uE-1] @ d-1
      // uE cell
      float bt0 = aE + q.x, lt0 = aO_up + labUp;
      float mx0 = fmaxf(bt0, lt0), mn0 = fminf(bt0, lt0);
      float r0 = mx0 + __log2f(1.0f + exp2f(mn0 - mx0));
      int te = d - uE;
      float nE = ((uE <= U_DIM) && (te >= 0) && (te < T_DIM)) ? r0 : NEG;
      // uO cell
      float bt1 = aO + q.z, lt1 = aE + q.y;
      float mx1 = fmaxf(bt1, lt1), mn1 = fminf(bt1, lt1);
      float r1 = mx1 + __log2f(1.0f + exp2f(mn1 - mx1));
      int to = te - 1;
      float nO = ((uE + 1 <= U_DIM) && (to >= 0) && (to < T_DIM)) ? r1 : NEG;
      aE = nE; aO = nO;
      if (d == dStar) {
        if (uIdx == uE)          ll2 = nE + blkStar;
        else if (uIdx == uE + 1) ll2 = nO + blkStar;
      }
    }
  }
#undef ISSUE

#pragma unroll
  for (int mask = 1; mask < 64; mask <<= 1) ll2 += __shfl_xor(ll2, mask, 64);
  if (lane == 0) llsh[wv] = ll2;
  __syncthreads();
  if (tid == 0)
    outLoss[0] = -(llsh[0] + llsh[1] + llsh[2] + llsh[3]) * 0.25f * LN2;
}

// ---------------- launch
extern "C" void kernel_launch(void* const* d_in, const int* in_sizes, int n_in,
                              void* d_out, int out_size, void* d_ws, size_t ws_size,
                              hipStream_t stream)
{
  const float* enc    = (const float*)d_in[0];
  const float* dec    = (const float*)d_in[1];
  const int*   tokens = (const int*)d_in[2];
  const int*   outLen = (const int*)d_in[3];
  const int*   tokLen = (const int*)d_in[4];
  const float* W1     = (const float*)d_in[5];
  const float* b1     = (const float*)d_in[6];
  const float* W2     = (const float*)d_in[7];
  const float* b2     = (const float*)d_in[8];
  float* out = (float*)d_out;

  char* ws = (char*)d_ws;
  float*   hEnc = (float*)(ws + 0);           // 800*512*4     = 1,638,400
  float*   hDec = (float*)(ws + 1638400);     // 404*512*4     =   827,392
  uchar_t* W2f8 = (uchar_t*)(ws + 2465792);   // 64*1024*8     =   524,288
  float*   pD   = (float*)(ws + 2990080);     // 4*300*128*2*4 = 1,228,800
                                              // + 8KB tail pad for dp chunk-37 overread (end 4,227,072)

  prep_kernel<<<dim3(215), dim3(512), 0, stream>>>(enc, dec, W1, W2, hEnc, hDec, W2f8);
  joint_kernel<<<dim3(26, 17, B_DIM), dim3(256), 0, stream>>>(hEnc, hDec, b1, W2f8, b2, tokens, pD);
  dp_kernel<<<dim3(1), dim3(256), 0, stream>>>(pD, outLen, tokLen, out);
}

// Round 9
// 265.823 us; speedup vs baseline: 1.2964x; 1.0405x over previous
//
#include <hip/hip_runtime.h>
#include <hip/hip_bf16.h>

#define T_DIM 200
#define U_DIM 100
#define U1    101
#define H_DIM 320
#define K_INNER 512
#define V_DIM 1000
#define B_DIM 4
#define ND 300            // diagonals d = t+u in [0, 299]
#define ROWS 48           // 12 t x 4 u per block
#define XPITCH 520        // 512 fp8 + 8B pad: conflict-free AND imm-offset addressable
#define CHUNK 8           // dp: diagonals per LDS chunk

typedef unsigned short ushort_t;
typedef unsigned char uchar_t;
typedef unsigned int uint32;
typedef long lfrag;       // 8 x fp8 = 2 VGPRs

typedef float ffrag4 __attribute__((ext_vector_type(4)));

#define LOG2E   1.4426950408889634f
#define LOG2E16 (1.4426950408889634f * 0.0625f)   // LOG2E/16 (W2 packed with x16 scale)
#define LN2     0.6931471805599453f

__device__ __forceinline__ float tanh_fast(float x) {
  float e = __expf(2.0f * x);                 // inf-safe: e=inf -> 1, e=0 -> -1
  return 1.0f - __fdividef(2.0f, e + 1.0f);
}

__device__ __forceinline__ uint2 pk_fp8x8(float t0, float t1, float t2, float t3,
                                          float t4, float t5, float t6, float t7) {
  uint2 r;
  r.x = (uint32)__builtin_amdgcn_cvt_pk_fp8_f32(t0, t1, 0, false);
  r.x = (uint32)__builtin_amdgcn_cvt_pk_fp8_f32(t2, t3, (int)r.x, true);
  r.y = (uint32)__builtin_amdgcn_cvt_pk_fp8_f32(t4, t5, 0, false);
  r.y = (uint32)__builtin_amdgcn_cvt_pk_fp8_f32(t6, t7, (int)r.y, true);
  return r;
}

// lane i <- lane i-1 (wave_shr:1 DPP, VALU-speed); invalid lane 0 gets `oldv`
__device__ __forceinline__ float dpp_up1(float v, float oldv) {
  return __int_as_float(__builtin_amdgcn_update_dpp(
      __float_as_int(oldv), __float_as_int(v), 0x138, 0xf, 0xf, false));
}

// ---------------- fused prep:
//   blocks [0,100):   h_enc projection (8 rows each)
//   blocks [100,151): h_dec projection (8 rows each)
//   blocks [151,215): W2 transpose-pack (x16 scale) -> W2f8[kchunk 64][n 1024][8 fp8]
__global__ __launch_bounds__(512)
void prep_kernel(const float* __restrict__ enc, const float* __restrict__ dec,
                 const float* __restrict__ W1, const float* __restrict__ W2,
                 float* __restrict__ hEnc, float* __restrict__ hDec,
                 uchar_t* __restrict__ W2f8)
{
  __shared__ union { float sIn[8][H_DIM]; float sW[8][1024]; } sh;
  const int tid = threadIdx.x;
  const int blk = blockIdx.x;

  if (blk < 151) {
    const float* inp; float* outp; int nRows, rowOff, b0;
    if (blk < 100) { inp = enc; outp = hEnc; nRows = B_DIM * T_DIM; rowOff = 0;     b0 = blk; }
    else           { inp = dec; outp = hDec; nRows = B_DIM * U1;    rowOff = H_DIM; b0 = blk - 100; }
    const int r0 = b0 * 8;
    for (int i = tid; i < 8 * H_DIM; i += 512) {
      int r = i / H_DIM, k = i - r * H_DIM;
      int rr = r0 + r;
      sh.sIn[r][k] = (rr < nRows) ? inp[(size_t)rr * H_DIM + k] : 0.0f;
    }
    __syncthreads();
    const int c = tid;  // 0..511
    float acc[8];
#pragma unroll
    for (int r = 0; r < 8; ++r) acc[r] = 0.0f;
    const float* Wp = W1 + (size_t)rowOff * K_INNER + c;
    for (int k = 0; k < H_DIM; k += 4) {
      float w0 = Wp[(size_t)(k + 0) * K_INNER];
      float w1 = Wp[(size_t)(k + 1) * K_INNER];
      float w2 = Wp[(size_t)(k + 2) * K_INNER];
      float w3 = Wp[(size_t)(k + 3) * K_INNER];
#pragma unroll
      for (int r = 0; r < 8; ++r) {
        float4 s = *(const float4*)&sh.sIn[r][k];
        acc[r] = fmaf(s.w, w3, fmaf(s.z, w2, fmaf(s.y, w1, fmaf(s.x, w0, acc[r]))));
      }
    }
#pragma unroll
    for (int r = 0; r < 8; ++r) {
      int rr = r0 + r;
      if (rr < nRows) outp[(size_t)rr * K_INNER + c] = acc[r];
    }
  } else {
    // W2 pack: kchunk kc covers k in [kc*8, kc*8+8); LDS transpose; x16 scale
    // (raw |w| <= 0.045 sits in e4m3's denormal zone; x16 -> +-0.71, normal)
    const int kc = blk - 151;
    for (int i = tid; i < 8 * 1024; i += 512) {
      int r = i >> 10, n = i & 1023;
      sh.sW[r][n] = (n < V_DIM) ? W2[(size_t)(kc * 8 + r) * V_DIM + n] : 0.0f;
    }
    __syncthreads();
#pragma unroll
    for (int h = 0; h < 2; ++h) {
      int n = tid + h * 512;
      uint2 pk = pk_fp8x8(sh.sW[0][n] * 16.f, sh.sW[1][n] * 16.f,
                          sh.sW[2][n] * 16.f, sh.sW[3][n] * 16.f,
                          sh.sW[4][n] * 16.f, sh.sW[5][n] * 16.f,
                          sh.sW[6][n] * 16.f, sh.sW[7][n] * 16.f);
      *(uint2*)&W2f8[((size_t)kc * 1024 + n) * 8] = pk;
    }
  }
}

// ---------------- fused joint, fp8, 48-row tile, padded-LDS (no swizzle), (256,3).
// X row pitch 520B: lane stride 2 dwords -> conflict-free b64 reads/writes, and
// A-addresses collapse to one loop-invariant base + immediate ds offsets
// (rb*8320 + ks*32 <= 17KB < 64KB imm). B reads: single pointer bumped +32768/ks.
// This removes the ~30 VALU/ks address arithmetic that made r8 VALU-bound
// (VALUBusy 65% vs MfmaUtil 32%).
__global__ __launch_bounds__(256, 3)
void joint_kernel(const float* __restrict__ hEnc, const float* __restrict__ hDec,
                  const float* __restrict__ b1, const uchar_t* __restrict__ W2f8,
                  const float* __restrict__ b2, const int* __restrict__ tokens,
                  float* __restrict__ pD)
{
  __shared__ union SU {
    uchar_t X[ROWS * XPITCH];     // 48 x 520 = 24,960 B
    float red[4][ROWS][4];
  } sh;

  const int tid = threadIdx.x;
  const int b  = blockIdx.z;
  const int t0 = blockIdx.y * 12;   // 17 blocks cover 200 (writes guarded)
  const int u0 = blockIdx.x * 4;    // 26 blocks cover 104 >= 101

  // ---- X staging: per pass a wave owns one row; G = lane -> conflict-free
  for (int i = tid; i < ROWS * 64; i += 256) {
    const int row = i >> 6;           // 0..47
    const int G = i & 63;
    const int tcl = min(t0 + (row >> 2), T_DIM - 1);
    const int ucl = min(u0 + (row & 3), U1 - 1);
    const float* er = hEnc + (size_t)(b * T_DIM + tcl) * K_INNER;
    const float* dr = hDec + (size_t)(b * U1 + ucl) * K_INNER;
    const int k = G << 3;
    float4 e0 = *(const float4*)(er + k);
    float4 e1 = *(const float4*)(er + k + 4);
    float4 d0 = *(const float4*)(dr + k);
    float4 d1 = *(const float4*)(dr + k + 4);
    float4 c0 = *(const float4*)(b1 + k);
    float4 c1 = *(const float4*)(b1 + k + 4);
    uint2 pk = pk_fp8x8(tanh_fast(e0.x + d0.x + c0.x), tanh_fast(e0.y + d0.y + c0.y),
                        tanh_fast(e0.z + d0.z + c0.z), tanh_fast(e0.w + d0.w + c0.w),
                        tanh_fast(e1.x + d1.x + c1.x), tanh_fast(e1.y + d1.y + c1.y),
                        tanh_fast(e1.z + d1.z + c1.z), tanh_fast(e1.w + d1.w + c1.w));
    *(uint2*)&sh.X[row * XPITCH + (G << 3)] = pk;
  }
  __syncthreads();

  const int wave = tid >> 6;
  const int lane = tid & 63;
  const int l15 = lane & 15;
  const int quad = lane >> 4;

  float sumexp[3][4], labelA[3][4], blankV[3][4];
#pragma unroll
  for (int i = 0; i < 3; ++i)
#pragma unroll
    for (int j = 0; j < 4; ++j) { sumexp[i][j] = 0.0f; labelA[i][j] = 0.0f; blankV[i][j] = 0.0f; }

  int tokv[4];
#pragma unroll
  for (int j = 0; j < 4; ++j)
    tokv[j] = (u0 + j < U_DIM) ? tokens[b * U_DIM + u0 + j] : -1;

  const uchar_t* aB = &sh.X[l15 * XPITCH + quad * 8];   // loop-invariant A base

#pragma unroll 1
  for (int ct = 0; ct < 4; ++ct) {
    const int nbase = ct * 256 + wave * 64;
    ffrag4 acc[3][4];
    ffrag4 zero4 = {0.0f, 0.0f, 0.0f, 0.0f};
#pragma unroll
    for (int rb = 0; rb < 3; ++rb)
#pragma unroll
      for (int cb = 0; cb < 4; ++cb) acc[rb][cb] = zero4;

    const uchar_t* bp = W2f8 + ((size_t)quad * 1024 + nbase + l15) * 8;

#pragma unroll 4
    for (int ks = 0; ks < 16; ++ks) {
      lfrag av[3];
#pragma unroll
      for (int rb = 0; rb < 3; ++rb)
        av[rb] = *(const lfrag*)(aB + rb * (16 * XPITCH) + ks * 32);
      lfrag bv[4];
#pragma unroll
      for (int cb = 0; cb < 4; ++cb)
        bv[cb] = *(const lfrag*)(bp + cb * 128);
      bp += 4 * 1024 * 8;   // next kchunk group
#pragma unroll
      for (int rb = 0; rb < 3; ++rb)
#pragma unroll
        for (int cb = 0; cb < 4; ++cb)
          acc[rb][cb] = __builtin_amdgcn_mfma_f32_16x16x32_fp8_fp8(av[rb], bv[cb], acc[rb][cb], 0, 0, 0);
    }

    // epilogue: acc = 16 x true logit (W2 scale); online sum(exp) via exp2
#pragma unroll
    for (int cb = 0; cb < 4; ++cb) {
      const int v = nbase + cb * 16 + l15;
      const float b2v = (v < V_DIM) ? b2[v] : -1e30f;
      const float b2s = b2v * LOG2E;
#pragma unroll
      for (int rb = 0; rb < 3; ++rb)
#pragma unroll
        for (int reg = 0; reg < 4; ++reg) {
          float a = acc[rb][cb][reg];
          sumexp[rb][reg] += exp2f(fmaf(a, LOG2E16, b2s));
          labelA[rb][reg] += (v == tokv[reg]) ? a : 0.0f;
        }
    }
    if (nbase == 0) {   // wave 0, ct 0: v==0 column lives on l15==0 lanes of cb 0
#pragma unroll
      for (int rb = 0; rb < 3; ++rb)
#pragma unroll
        for (int reg = 0; reg < 4; ++reg) blankV[rb][reg] = acc[rb][0][reg];
    }
  }

#pragma unroll
  for (int mask = 1; mask <= 8; mask <<= 1) {
#pragma unroll
    for (int rb = 0; rb < 3; ++rb)
#pragma unroll
      for (int reg = 0; reg < 4; ++reg) {
        sumexp[rb][reg] += __shfl_xor(sumexp[rb][reg], mask, 64);
        labelA[rb][reg] += __shfl_xor(labelA[rb][reg], mask, 64);
      }
  }

  __syncthreads();   // X reads done -> reuse union as red[]
  if (l15 == 0) {
#pragma unroll
    for (int rb = 0; rb < 3; ++rb)
#pragma unroll
      for (int reg = 0; reg < 4; ++reg) {
        int row = rb * 16 + quad * 4 + reg;
        sh.red[wave][row][0] = sumexp[rb][reg];
        sh.red[wave][row][1] = blankV[rb][reg];
        sh.red[wave][row][2] = labelA[rb][reg];
      }
  }
  __syncthreads();
  if (tid < ROWS) {
    float S  = sh.red[0][tid][0] + sh.red[1][tid][0] + sh.red[2][tid][0] + sh.red[3][tid][0];
    float Bl = sh.red[0][tid][1] + sh.red[1][tid][1] + sh.red[2][tid][1] + sh.red[3][tid][1];
    float Lb = sh.red[0][tid][2] + sh.red[1][tid][2] + sh.red[2][tid][2] + sh.red[3][tid][2];
    int t = t0 + (tid >> 2);
    int u = u0 + (tid & 3);
    if (t < T_DIM && u < U1) {
      float lse2 = __log2f(S);                 // S = sum(exp(true logit))
      int tok = (u < U_DIM) ? tokens[b * U_DIM + u] : 0;
      int d = t + u;
      size_t idx = (((size_t)b * ND + d) * 128 + u) * 2;
      pD[idx]     = fmaf(Bl, LOG2E16, b2[0]   * LOG2E) - lse2;   // blank
      pD[idx + 1] = fmaf(Lb, LOG2E16, b2[tok] * LOG2E) - lse2;   // label
    }
  }
}

// ---------------- RNNT DP, log2 domain, LDS-staged triple-buffered chunks,
// DPP wave_shr:1 for the serial cross-lane (VALU-speed vs ds_bpermute ~40cyc).
// DMA distance 2 (vmcnt(16)): chunk latency (~900cyc) covered by 16 steps.
__global__ __launch_bounds__(256)
void dp_kernel(const float* __restrict__ pD,
               const int* __restrict__ outLen, const int* __restrict__ tokLen,
               float* __restrict__ outLoss)
{
  __shared__ float sD[4][3][CHUNK * 256];   // 96 KB: per-wave triple buffer
  __shared__ float llsh[B_DIM];
  const int tid = threadIdx.x;
  const int wv = tid >> 6;                  // wave = batch
  const int lane = tid & 63;
  const float* src = pD + (size_t)wv * ND * 256;
  const int tIdx = outLen[wv] - 1;
  const int uIdx = tokLen[wv];
  const int dStar = tIdx + uIdx;
  const float NEG = -1e30f;
  const float blkStar = src[((size_t)dStar * 128 + uIdx) * 2];

  float aE = (lane == 0) ? 0.0f : NEG;      // log2 domain
  float aO = NEG;
  float ll2 = 0.0f;
  if (dStar == 0 && lane == 0) ll2 = blkStar;

  const int uE = 2 * lane;

#define ISSUE(c, buf)                                                         \
  {                                                                           \
    const float* g_ = src + (size_t)(c) * (CHUNK * 256);                      \
    float* l_ = &sD[wv][(buf)][0];                                            \
    _Pragma("unroll")                                                         \
    for (int j_ = 0; j_ < CHUNK; ++j_)                                        \
      __builtin_amdgcn_global_load_lds(                                       \
        (const __attribute__((address_space(1))) void*)(g_ + j_ * 256 + lane * 4), \
        (__attribute__((address_space(3))) void*)(l_ + j_ * 256), 16, 0, 0);  \
  }

  ISSUE(0, 0)
  ISSUE(1, 1)
#pragma unroll 1
  for (int c = 0; c < 38; ++c) {
    { const int nc = c + 2; const int cc = nc <= 37 ? nc : 37; ISSUE(cc, nc % 3) }
    asm volatile("s_waitcnt vmcnt(16)" ::: "memory");   // chunk c resident
    const float* buf = &sD[wv][c % 3][0];
#pragma unroll
    for (int j = 0; j < CHUNK; ++j) {
      const int d = c * CHUNK + 1 + j;
      float4 q = *(const float4*)&buf[j * 256 + uE * 2];
      // q = (B[uE], L[uE], B[uE+1], L[uE+1]) at source diag d-1
      float aO_up = dpp_up1(aO, NEG);
      float labUp = dpp_up1(q.w, NEG);                // L[uE-1] @ d-1
      // uE cell
      float bt0 = aE + q.x, lt0 = aO_up + labUp;
      float mx0 = fmaxf(bt0, lt0), mn0 = fminf(bt0, lt0);
      float r0 = mx0 + __log2f(1.0f + exp2f(mn0 - mx0));
      int te = d - uE;
      float nE = ((uE <= U_DIM) && (te >= 0) && (te < T_DIM)) ? r0 : NEG;
      // uO cell
      float bt1 = aO + q.z, lt1 = aE + q.y;
      float mx1 = fmaxf(bt1, lt1), mn1 = fminf(bt1, lt1);
      float r1 = mx1 + __log2f(1.0f + exp2f(mn1 - mx1));
      int to = te - 1;
      float nO = ((uE + 1 <= U_DIM) && (to >= 0) && (to < T_DIM)) ? r1 : NEG;
      aE = nE; aO = nO;
      if (d == dStar) {
        if (uIdx == uE)          ll2 = nE + blkStar;
        else if (uIdx == uE + 1) ll2 = nO + blkStar;
      }
    }
  }
#undef ISSUE

#pragma unroll
  for (int mask = 1; mask < 64; mask <<= 1) ll2 += __shfl_xor(ll2, mask, 64);
  if (lane == 0) llsh[wv] = ll2;
  __syncthreads();
  if (tid == 0)
    outLoss[0] = -(llsh[0] + llsh[1] + llsh[2] + llsh[3]) * 0.25f * LN2;
}

// ---------------- launch
extern "C" void kernel_launch(void* const* d_in, const int* in_sizes, int n_in,
                              void* d_out, int out_size, void* d_ws, size_t ws_size,
                              hipStream_t stream)
{
  const float* enc    = (const float*)d_in[0];
  const float* dec    = (const float*)d_in[1];
  const int*   tokens = (const int*)d_in[2];
  const int*   outLen = (const int*)d_in[3];
  const int*   tokLen = (const int*)d_in[4];
  const float* W1     = (const float*)d_in[5];
  const float* b1     = (const float*)d_in[6];
  const float* W2     = (const float*)d_in[7];
  const float* b2     = (const float*)d_in[8];
  float* out = (float*)d_out;

  char* ws = (char*)d_ws;
  float*   hEnc = (float*)(ws + 0);           // 800*512*4     = 1,638,400
  float*   hDec = (float*)(ws + 1638400);     // 404*512*4     =   827,392
  uchar_t* W2f8 = (uchar_t*)(ws + 2465792);   // 64*1024*8     =   524,288
  float*   pD   = (float*)(ws + 2990080);     // 4*300*128*2*4 = 1,228,800
                                              // + 16KB tail pad for dp chunk-37 overread

  prep_kernel<<<dim3(215), dim3(512), 0, stream>>>(enc, dec, W1, W2, hEnc, hDec, W2f8);
  joint_kernel<<<dim3(26, 17, B_DIM), dim3(256), 0, stream>>>(hEnc, hDec, b1, W2f8, b2, tokens, pD);
  dp_kernel<<<dim3(1), dim3(256), 0, stream>>>(pD, outLen, tokLen, out);
}

// Round 10
// 257.889 us; speedup vs baseline: 1.3363x; 1.0308x over previous
//
#include <hip/hip_runtime.h>
#include <hip/hip_bf16.h>

#define T_DIM 200
#define U_DIM 100
#define U1    101
#define H_DIM 320
#define K_INNER 512
#define V_DIM 1000
#define B_DIM 4
#define ND 300            // diagonals d = t+u in [0, 299]
#define ROWS 48           // 12 t x 4 u per block
#define XPITCH 520        // 512 fp8 + 8B pad: conflict-free + imm-offset addressable
#define CHUNK 8           // dp: diagonals per LDS chunk

typedef unsigned short ushort_t;
typedef unsigned char uchar_t;
typedef unsigned int uint32;
typedef long lfrag;       // 8 x fp8 = 2 VGPRs

typedef float ffrag4 __attribute__((ext_vector_type(4)));

#define LOG2E   1.4426950408889634f
#define LOG2E16 (1.4426950408889634f * 0.0625f)   // LOG2E/16 (W2 packed with x16 scale)
#define LN2     0.6931471805599453f

__device__ __forceinline__ float tanh_fast(float x) {
  float e = __expf(2.0f * x);                 // inf-safe: e=inf -> 1, e=0 -> -1
  return 1.0f - __fdividef(2.0f, e + 1.0f);
}

__device__ __forceinline__ uint2 pk_fp8x8(float t0, float t1, float t2, float t3,
                                          float t4, float t5, float t6, float t7) {
  uint2 r;
  r.x = (uint32)__builtin_amdgcn_cvt_pk_fp8_f32(t0, t1, 0, false);
  r.x = (uint32)__builtin_amdgcn_cvt_pk_fp8_f32(t2, t3, (int)r.x, true);
  r.y = (uint32)__builtin_amdgcn_cvt_pk_fp8_f32(t4, t5, 0, false);
  r.y = (uint32)__builtin_amdgcn_cvt_pk_fp8_f32(t6, t7, (int)r.y, true);
  return r;
}

// lane i <- lane i-1 (wave_shr:1 DPP, VALU-speed); invalid lane 0 gets `oldv`
__device__ __forceinline__ float dpp_up1(float v, float oldv) {
  return __int_as_float(__builtin_amdgcn_update_dpp(
      __float_as_int(oldv), __float_as_int(v), 0x138, 0xf, 0xf, false));
}

// ---------------- fused prep:
//   blocks [0,100):   h_enc projection (8 rows each)
//   blocks [100,151): h_dec projection (8 rows each)
//   blocks [151,215): W2 transpose-pack (x16 scale) into DMA-tile layout:
//     byte offset(kc, n) = (ct*16+ks)*8192 + w*2048 + q*512 + col*8
//     where ks=kc>>2, q=kc&3, ct=n>>8, w=(n>>6)&3, col=n&63.
//     Tile (ct,ks) = exactly the 8KB a joint block consumes per K-step, laid out
//     so each wave's 2KB slice is contiguous in lane-DMA order.
__global__ __launch_bounds__(512)
void prep_kernel(const float* __restrict__ enc, const float* __restrict__ dec,
                 const float* __restrict__ W1, const float* __restrict__ W2,
                 float* __restrict__ hEnc, float* __restrict__ hDec,
                 uchar_t* __restrict__ W2f8)
{
  __shared__ union { float sIn[8][H_DIM]; float sW[8][1024]; } sh;
  const int tid = threadIdx.x;
  const int blk = blockIdx.x;

  if (blk < 151) {
    const float* inp; float* outp; int nRows, rowOff, b0;
    if (blk < 100) { inp = enc; outp = hEnc; nRows = B_DIM * T_DIM; rowOff = 0;     b0 = blk; }
    else           { inp = dec; outp = hDec; nRows = B_DIM * U1;    rowOff = H_DIM; b0 = blk - 100; }
    const int r0 = b0 * 8;
    for (int i = tid; i < 8 * H_DIM; i += 512) {
      int r = i / H_DIM, k = i - r * H_DIM;
      int rr = r0 + r;
      sh.sIn[r][k] = (rr < nRows) ? inp[(size_t)rr * H_DIM + k] : 0.0f;
    }
    __syncthreads();
    const int c = tid;  // 0..511
    float acc[8];
#pragma unroll
    for (int r = 0; r < 8; ++r) acc[r] = 0.0f;
    const float* Wp = W1 + (size_t)rowOff * K_INNER + c;
    for (int k = 0; k < H_DIM; k += 4) {
      float w0 = Wp[(size_t)(k + 0) * K_INNER];
      float w1 = Wp[(size_t)(k + 1) * K_INNER];
      float w2 = Wp[(size_t)(k + 2) * K_INNER];
      float w3 = Wp[(size_t)(k + 3) * K_INNER];
#pragma unroll
      for (int r = 0; r < 8; ++r) {
        float4 s = *(const float4*)&sh.sIn[r][k];
        acc[r] = fmaf(s.w, w3, fmaf(s.z, w2, fmaf(s.y, w1, fmaf(s.x, w0, acc[r]))));
      }
    }
#pragma unroll
    for (int r = 0; r < 8; ++r) {
      int rr = r0 + r;
      if (rr < nRows) outp[(size_t)rr * K_INNER + c] = acc[r];
    }
  } else {
    // W2 pack: kchunk kc covers k in [kc*8, kc*8+8); LDS transpose; x16 scale
    // (raw |w| <= 0.045 sits in e4m3's denormal zone; x16 -> +-0.71, normal)
    const int kc = blk - 151;
    for (int i = tid; i < 8 * 1024; i += 512) {
      int r = i >> 10, n = i & 1023;
      sh.sW[r][n] = (n < V_DIM) ? W2[(size_t)(kc * 8 + r) * V_DIM + n] : 0.0f;
    }
    __syncthreads();
    const int ks = kc >> 2, q = kc & 3;
#pragma unroll
    for (int h = 0; h < 2; ++h) {
      int n = tid + h * 512;
      uint2 pk = pk_fp8x8(sh.sW[0][n] * 16.f, sh.sW[1][n] * 16.f,
                          sh.sW[2][n] * 16.f, sh.sW[3][n] * 16.f,
                          sh.sW[4][n] * 16.f, sh.sW[5][n] * 16.f,
                          sh.sW[6][n] * 16.f, sh.sW[7][n] * 16.f);
      const int ct = n >> 8, w = (n >> 6) & 3, col = n & 63;
      const size_t off = (size_t)(ct * 16 + ks) * 8192 + w * 2048 + q * 512 + col * 8;
      *(uint2*)&W2f8[off] = pk;
    }
  }
}

// ---------------- fused joint, fp8, 48-row tile, (256,3).
// K-loop B-feed: per-wave global_load_lds double-buffer (2KB slices, 2x16B
// issues/stage, strict vmcnt(2)) -- r9 evidence: per-wave global B loads were
// latency-exposed (MfmaUtil stuck at 32% after conflicts+VALU were removed).
// b2/tokens preloaded to regs BEFORE the staging __syncthreads (barrier drains
// vmcnt(0)) so the K-loop's vmcnt accounting sees only my DMA issues.
__global__ __launch_bounds__(256, 3)
void joint_kernel(const float* __restrict__ hEnc, const float* __restrict__ hDec,
                  const float* __restrict__ b1, const uchar_t* __restrict__ W2f8,
                  const float* __restrict__ b2, const int* __restrict__ tokens,
                  float* __restrict__ pD)
{
  __shared__ union SU {
    uchar_t X[ROWS * XPITCH];     // 48 x 520 = 24,960 B
    float red[4][ROWS][4];
  } sh;
  __shared__ __align__(16) uchar_t sB[4][2][2048];   // per-wave B double buffer (16KB)

  const int tid = threadIdx.x;
  const int b  = blockIdx.z;
  const int t0 = blockIdx.y * 12;   // 17 blocks cover 200 (writes guarded)
  const int u0 = blockIdx.x * 4;    // 26 blocks cover 104 >= 101
  const int wave = tid >> 6;
  const int lane = tid & 63;
  const int l15 = lane & 15;
  const int quad = lane >> 4;

  // preload b2 (scaled) + tokens to regs; they retire at the staging barrier
  float b2s[4][4];
#pragma unroll
  for (int ct = 0; ct < 4; ++ct)
#pragma unroll
    for (int cb = 0; cb < 4; ++cb) {
      int v = ct * 256 + wave * 64 + cb * 16 + l15;
      b2s[ct][cb] = (v < V_DIM) ? b2[v] * LOG2E : -1e30f;
    }
  int tokv[4];
#pragma unroll
  for (int j = 0; j < 4; ++j)
    tokv[j] = (u0 + j < U_DIM) ? tokens[b * U_DIM + u0 + j] : -1;

  // ---- X staging: per pass a wave owns one row; G = lane -> conflict-free
  for (int i = tid; i < ROWS * 64; i += 256) {
    const int row = i >> 6;           // 0..47
    const int G = i & 63;
    const int tcl = min(t0 + (row >> 2), T_DIM - 1);
    const int ucl = min(u0 + (row & 3), U1 - 1);
    const float* er = hEnc + (size_t)(b * T_DIM + tcl) * K_INNER;
    const float* dr = hDec + (size_t)(b * U1 + ucl) * K_INNER;
    const int k = G << 3;
    float4 e0 = *(const float4*)(er + k);
    float4 e1 = *(const float4*)(er + k + 4);
    float4 d0 = *(const float4*)(dr + k);
    float4 d1 = *(const float4*)(dr + k + 4);
    float4 c0 = *(const float4*)(b1 + k);
    float4 c1 = *(const float4*)(b1 + k + 4);
    uint2 pk = pk_fp8x8(tanh_fast(e0.x + d0.x + c0.x), tanh_fast(e0.y + d0.y + c0.y),
                        tanh_fast(e0.z + d0.z + c0.z), tanh_fast(e0.w + d0.w + c0.w),
                        tanh_fast(e1.x + d1.x + c1.x), tanh_fast(e1.y + d1.y + c1.y),
                        tanh_fast(e1.z + d1.z + c1.z), tanh_fast(e1.w + d1.w + c1.w));
    *(uint2*)&sh.X[row * XPITCH + (G << 3)] = pk;
  }
  __syncthreads();   // drains vmcnt(0): all loads above retired

  uchar_t* sBw = &sB[wave][0][0];
  const uchar_t* gW = W2f8 + (size_t)wave * 2048 + (size_t)lane * 16;

#define STAGE(gbase, bufv)                                                          \
  {                                                                                 \
    __builtin_amdgcn_global_load_lds(                                               \
        (const __attribute__((address_space(1))) void*)(gbase),                     \
        (__attribute__((address_space(3))) void*)(sBw + (bufv) * 2048), 16, 0, 0);  \
    __builtin_amdgcn_global_load_lds(                                               \
        (const __attribute__((address_space(1))) void*)((gbase) + 1024),            \
        (__attribute__((address_space(3))) void*)(sBw + (bufv) * 2048 + 1024), 16, 0, 0); \
  }

  STAGE(gW, 0)                       // tile (ct=0, ks=0)
  const uchar_t* gP = gW + 8192;     // next tile; tiles laid out [ct][ks] contiguously

  const uchar_t* aB = &sh.X[l15 * XPITCH + quad * 8];   // loop-invariant A base
  const uchar_t* bL = sBw + quad * 512 + l15 * 8;       // loop-invariant B base

  float sumexp[3][4], labelA[3][4], blankV[3][4];
#pragma unroll
  for (int i = 0; i < 3; ++i)
#pragma unroll
    for (int j = 0; j < 4; ++j) { sumexp[i][j] = 0.0f; labelA[i][j] = 0.0f; blankV[i][j] = 0.0f; }

#pragma unroll 1
  for (int ct = 0; ct < 4; ++ct) {
    ffrag4 acc[3][4];
    ffrag4 zero4 = {0.0f, 0.0f, 0.0f, 0.0f};
#pragma unroll
    for (int rb = 0; rb < 3; ++rb)
#pragma unroll
      for (int cb = 0; cb < 4; ++cb) acc[rb][cb] = zero4;

#pragma unroll
    for (int ks = 0; ks < 16; ++ks) {
      if (ks < 15 || ct < 3) {                // issue next stage, keep 1 in flight
        STAGE(gP, (ks + 1) & 1)
        gP += 8192;
        asm volatile("s_waitcnt vmcnt(2)" ::: "memory");   // current stage resident
      } else {
        asm volatile("s_waitcnt vmcnt(0)" ::: "memory");
      }
      lfrag av[3];
#pragma unroll
      for (int rb = 0; rb < 3; ++rb)
        av[rb] = *(const lfrag*)(aB + rb * (16 * XPITCH) + ks * 32);
      lfrag bv[4];
#pragma unroll
      for (int cb = 0; cb < 4; ++cb)
        bv[cb] = *(const lfrag*)(bL + (ks & 1) * 2048 + cb * 128);
#pragma unroll
      for (int rb = 0; rb < 3; ++rb)
#pragma unroll
        for (int cb = 0; cb < 4; ++cb)
          acc[rb][cb] = __builtin_amdgcn_mfma_f32_16x16x32_fp8_fp8(av[rb], bv[cb], acc[rb][cb], 0, 0, 0);
    }

    // epilogue: acc = 16 x true logit (W2 scale); registers only (no vmem)
#pragma unroll
    for (int cb = 0; cb < 4; ++cb) {
      const int v = ct * 256 + wave * 64 + cb * 16 + l15;
      const float bs = b2s[ct][cb];
#pragma unroll
      for (int rb = 0; rb < 3; ++rb)
#pragma unroll
        for (int reg = 0; reg < 4; ++reg) {
          float a = acc[rb][cb][reg];
          sumexp[rb][reg] += exp2f(fmaf(a, LOG2E16, bs));
          labelA[rb][reg] += (v == tokv[reg]) ? a : 0.0f;
        }
    }
    if (ct == 0 && wave == 0) {   // v==0 column lives on l15==0 lanes of cb 0
#pragma unroll
      for (int rb = 0; rb < 3; ++rb)
#pragma unroll
        for (int reg = 0; reg < 4; ++reg) blankV[rb][reg] = acc[rb][0][reg];
    }
  }
#undef STAGE

#pragma unroll
  for (int mask = 1; mask <= 8; mask <<= 1) {
#pragma unroll
    for (int rb = 0; rb < 3; ++rb)
#pragma unroll
      for (int reg = 0; reg < 4; ++reg) {
        sumexp[rb][reg] += __shfl_xor(sumexp[rb][reg], mask, 64);
        labelA[rb][reg] += __shfl_xor(labelA[rb][reg], mask, 64);
      }
  }

  __syncthreads();   // X reads done -> reuse union as red[]
  if (l15 == 0) {
#pragma unroll
    for (int rb = 0; rb < 3; ++rb)
#pragma unroll
      for (int reg = 0; reg < 4; ++reg) {
        int row = rb * 16 + quad * 4 + reg;
        sh.red[wave][row][0] = sumexp[rb][reg];
        sh.red[wave][row][1] = blankV[rb][reg];
        sh.red[wave][row][2] = labelA[rb][reg];
      }
  }
  __syncthreads();
  if (tid < ROWS) {
    float S  = sh.red[0][tid][0] + sh.red[1][tid][0] + sh.red[2][tid][0] + sh.red[3][tid][0];
    float Bl = sh.red[0][tid][1] + sh.red[1][tid][1] + sh.red[2][tid][1] + sh.red[3][tid][1];
    float Lb = sh.red[0][tid][2] + sh.red[1][tid][2] + sh.red[2][tid][2] + sh.red[3][tid][2];
    int t = t0 + (tid >> 2);
    int u = u0 + (tid & 3);
    if (t < T_DIM && u < U1) {
      float lse2 = __log2f(S);                 // S = sum(exp(true logit))
      int tok = (u < U_DIM) ? tokens[b * U_DIM + u] : 0;
      int d = t + u;
      size_t idx = (((size_t)b * ND + d) * 128 + u) * 2;
      pD[idx]     = fmaf(Bl, LOG2E16, b2[0]   * LOG2E) - lse2;   // blank
      pD[idx + 1] = fmaf(Lb, LOG2E16, b2[tok] * LOG2E) - lse2;   // label
    }
  }
}

// ---------------- RNNT DP, log2 domain, LDS-staged triple-buffered chunks.
// r9 residual (~100us, ~330cyc/step): per-step ds_read latency sat on the serial
// chain. Fix: batch all 8 q-reads of a chunk into registers (unrolled float4
// qv[8]) before the 8-step chain -- LDS latency paid once per chunk.
__global__ __launch_bounds__(256)
void dp_kernel(const float* __restrict__ pD,
               const int* __restrict__ outLen, const int* __restrict__ tokLen,
               float* __restrict__ outLoss)
{
  __shared__ __align__(16) float sD[4][3][CHUNK * 256];   // 96 KB triple buffer
  __shared__ float llsh[B_DIM];
  const int tid = threadIdx.x;
  const int wv = tid >> 6;                  // wave = batch
  const int lane = tid & 63;
  const float* src = pD + (size_t)wv * ND * 256;
  const int tIdx = outLen[wv] - 1;
  const int uIdx = tokLen[wv];
  const int dStar = tIdx + uIdx;
  const float NEG = -1e30f;
  const float blkStar = src[((size_t)dStar * 128 + uIdx) * 2];

  float aE = (lane == 0) ? 0.0f : NEG;      // log2 domain
  float aO = NEG;
  float ll2 = 0.0f;
  if (dStar == 0 && lane == 0) ll2 = blkStar;

  const int uE = 2 * lane;

#define ISSUE(c, buf)                                                         \
  {                                                                           \
    const float* g_ = src + (size_t)(c) * (CHUNK * 256);                      \
    float* l_ = &sD[wv][(buf)][0];                                            \
    _Pragma("unroll")                                                         \
    for (int j_ = 0; j_ < CHUNK; ++j_)                                        \
      __builtin_amdgcn_global_load_lds(                                       \
        (const __attribute__((address_space(1))) void*)(g_ + j_ * 256 + lane * 4), \
        (__attribute__((address_space(3))) void*)(l_ + j_ * 256), 16, 0, 0);  \
  }

  ISSUE(0, 0)
  ISSUE(1, 1)
#pragma unroll 1
  for (int c = 0; c < 38; ++c) {
    { const int nc = c + 2; const int cc = nc <= 37 ? nc : 37; ISSUE(cc, nc % 3) }
    asm volatile("s_waitcnt vmcnt(16)" ::: "memory");   // chunk c resident
    const float* buf = &sD[wv][c % 3][0];
    float4 qv[CHUNK];
#pragma unroll
    for (int j = 0; j < CHUNK; ++j)
      qv[j] = *(const float4*)&buf[j * 256 + uE * 2];
#pragma unroll
    for (int j = 0; j < CHUNK; ++j) {
      const int d = c * CHUNK + 1 + j;
      float4 q = qv[j];
      // q = (B[uE], L[uE], B[uE+1], L[uE+1]) at source diag d-1
      float aO_up = dpp_up1(aO, NEG);
      float labUp = dpp_up1(q.w, NEG);                // L[uE-1] @ d-1
      // uE cell
      float bt0 = aE + q.x, lt0 = aO_up + labUp;
      float mx0 = fmaxf(bt0, lt0), mn0 = fminf(bt0, lt0);
      float r0 = mx0 + __log2f(1.0f + exp2f(mn0 - mx0));
      int te = d - uE;
      float nE = ((uE <= U_DIM) && (te >= 0) && (te < T_DIM)) ? r0 : NEG;
      // uO cell
      float bt1 = aO + q.z, lt1 = aE + q.y;
      float mx1 = fmaxf(bt1, lt1), mn1 = fminf(bt1, lt1);
      float r1 = mx1 + __log2f(1.0f + exp2f(mn1 - mx1));
      int to = te - 1;
      float nO = ((uE + 1 <= U_DIM) && (to >= 0) && (to < T_DIM)) ? r1 : NEG;
      aE = nE; aO = nO;
      if (d == dStar) {
        if (uIdx == uE)          ll2 = nE + blkStar;
        else if (uIdx == uE + 1) ll2 = nO + blkStar;
      }
    }
  }
#undef ISSUE

#pragma unroll
  for (int mask = 1; mask < 64; mask <<= 1) ll2 += __shfl_xor(ll2, mask, 64);
  if (lane == 0) llsh[wv] = ll2;
  __syncthreads();
  if (tid == 0)
    outLoss[0] = -(llsh[0] + llsh[1] + llsh[2] + llsh[3]) * 0.25f * LN2;
}

// ---------------- launch
extern "C" void kernel_launch(void* const* d_in, const int* in_sizes, int n_in,
                              void* d_out, int out_size, void* d_ws, size_t ws_size,
                              hipStream_t stream)
{
  const float* enc    = (const float*)d_in[0];
  const float* dec    = (const float*)d_in[1];
  const int*   tokens = (const int*)d_in[2];
  const int*   outLen = (const int*)d_in[3];
  const int*   tokLen = (const int*)d_in[4];
  const float* W1     = (const float*)d_in[5];
  const float* b1     = (const float*)d_in[6];
  const float* W2     = (const float*)d_in[7];
  const float* b2     = (const float*)d_in[8];
  float* out = (float*)d_out;

  char* ws = (char*)d_ws;
  float*   hEnc = (float*)(ws + 0);           // 800*512*4     = 1,638,400
  float*   hDec = (float*)(ws + 1638400);     // 404*512*4     =   827,392
  uchar_t* W2f8 = (uchar_t*)(ws + 2465792);   // 64 tiles*8192 =   524,288 (16-aligned)
  float*   pD   = (float*)(ws + 2990080);     // 4*300*128*2*4 = 1,228,800
                                              // + 16KB tail pad for dp chunk-37 overread

  prep_kernel<<<dim3(215), dim3(512), 0, stream>>>(enc, dec, W1, W2, hEnc, hDec, W2f8);
  joint_kernel<<<dim3(26, 17, B_DIM), dim3(256), 0, stream>>>(hEnc, hDec, b1, W2f8, b2, tokens, pD);
  dp_kernel<<<dim3(1), dim3(256), 0, stream>>>(pD, outLen, tokLen, out);
}